// Round 10
// baseline (4047.275 us; speedup 1.0000x reference)
//
#include <hip/hip_runtime.h>

// LSTM encoder-decoder, MI355X. B=1024, S=256, IN=8, H=512, F=96.
// R16: 512 wgs x 256 thr = 2 blocks/CU, 32 groups x 32 rows; spill-safe staging.
// R13/R14/R15 NaN theory (3rd iteration): at the 256-VGPR cap, the RA may SPILL an
// asm-load destination register between issue and the separate manual vmcnt — the
// spill captures an in-flight (garbage) value. Compiler can't know better: the asm
// block "defines" the reg at issue. Fix: ONE asm block = 8x global_load_dwordx4 +
// s_waitcnt vmcnt(0) INSIDE, early-clobber outputs -> d0..d7 are defined complete;
// any later spill is of a correct value. x via compiler float4 loads (tracked).
// Drops R12's intra-step phasing; relies on 2-waves/SIMD cross-block overlap.
// Kept verified pieces: R14 sound self-org (RELEASE arrive++/ACQUIRE spin/fence),
// RMW-only cross-wg polls, h1 zeroed, 2-tile pointwise (lane-algebra re-derived).
// !! HARD RULES: (1) cross-wg spin-waits are atomic-RMW ONLY (load-polls hang:
// R7/R8/R11). (2) asm-load destinations must be completed INSIDE the defining asm
// block (waitcnt in-block) whenever VGPR pressure is high. (3) launch_bounds 2nd
// arg is min BLOCKS/CU: (256,2)->cap 256 ok; 512-thr blocks banned (R9/R10).
// If this round NaNs: abandon 2-blk/CU permanently, revert to R12 (2451us).
// Mode A: XCD-self-organized groups (4/XCD), h via XCD-local L2 (plain stores +
// sc0 loads), barrier = TCC atomics. Mode B fallback: agent-scope MALL path.

#define Hh 512
#define K2 544       // 512 h + 8 x + 24 zero pad
#define BATCH 1024
#define SEQ 256
#define FCAST 96
#define Mrows 32
#define SAS 552      // sA stride (f16)
#define SHS 40       // sH stride (f16): 80 B row

typedef _Float16 f16;
typedef _Float16 f16x8 __attribute__((ext_vector_type(8)));
typedef float f32x4 __attribute__((ext_vector_type(4)));

__device__ __forceinline__ float sigf(float v) { return 1.0f / (1.0f + __expf(-v)); }
__device__ __forceinline__ float tanhf_(float v) { return 1.0f - 2.0f / (__expf(2.0f * v) + 1.0f); }

__device__ __forceinline__ void st16(f16* p, f16x8 v, bool byp) {
  if (byp) asm volatile("global_store_dwordx4 %0, %1, off sc0 sc1" :: "v"(p), "v"(v) : "memory");
  else     asm volatile("global_store_dwordx4 %0, %1, off"         :: "v"(p), "v"(v) : "memory");
}
__device__ __forceinline__ int atomic_add_l2(int* p, int v) {
  int old;
  asm volatile("global_atomic_add %0, %1, %2, off sc0\n\ts_waitcnt vmcnt(0)"
               : "=v"(old) : "v"(p), "v"(v) : "memory");
  return old;
}

// ---------------- prep: permute + fp16-convert + fold weights ----------------
// global col n: nslot=n>>7, c=n&127, w=c>>5, cc=c&31, ct=cc>>4, l4=cc&15;
// gate=ct*2+(l4>>3), j=l4&7, unit=nslot*32+w*8+j; source row r=gate*512+unit.
// K: [0,512)=Whh, [512,520)=Wih(enc), [520,544)=0.
__global__ void prep_weights(const float* __restrict__ encWih, const float* __restrict__ encWhh,
                             const float* __restrict__ decWih, const float* __restrict__ decWhh,
                             const float* __restrict__ encBih, const float* __restrict__ encBhh,
                             const float* __restrict__ decBih, const float* __restrict__ decBhh,
                             const float* __restrict__ outW, const float* __restrict__ outB,
                             f16* __restrict__ encT, f16* __restrict__ decPW, f16* __restrict__ decFW,
                             float* __restrict__ bE, float* __restrict__ bP, float* __restrict__ bF) {
  int id = blockIdx.x * 256 + threadIdx.x;
  if (id >= 2048 * 68) return;
  int n = id / 68, c8 = id % 68;
  int nslot = n >> 7, c = n & 127, w = c >> 5, cc = c & 31, ct = cc >> 4, l4v = cc & 15;
  int g = ct * 2 + (l4v >> 3), j = l4v & 7;
  int unit = nslot * 32 + w * 8 + j, r = g * Hh + unit;
  size_t o = (size_t)n * K2 + c8 * 8;
  if (c8 < 64) {
    float dwih = decWih[r];
#pragma unroll
    for (int e = 0; e < 8; ++e) {
      int k = c8 * 8 + e;
      encT[o + e] = (f16)encWhh[(size_t)r * Hh + k];
      float dw = decWhh[(size_t)r * Hh + k];
      decPW[o + e] = (f16)dw;
      decFW[o + e] = (f16)(dw + outW[k] * dwih);
    }
  } else if (c8 == 64) {
#pragma unroll
    for (int e = 0; e < 8; ++e) {
      encT[o + e] = (f16)encWih[r * 8 + e];
      decPW[o + e] = (f16)0.f;
      decFW[o + e] = (f16)0.f;
    }
  } else {
#pragma unroll
    for (int e = 0; e < 8; ++e) {
      encT[o + e] = (f16)0.f;
      decPW[o + e] = (f16)0.f;
      decFW[o + e] = (f16)0.f;
    }
  }
  if (c8 == 0) {
    bE[n] = encBih[r] + encBhh[r];
    float bd = decBih[r] + decBhh[r];
    bP[n] = bd;
    bF[n] = bd + outB[0] * decWih[r];
  }
}

__global__ void init_state(f16* __restrict__ h0, f16* __restrict__ h1, float* __restrict__ out,
                           const float* __restrict__ outB, int* __restrict__ sync) {
  int i = blockIdx.x * 256 + threadIdx.x;
  if (i < BATCH * Hh) { h0[i] = (f16)0.f; h1[i] = (f16)0.f; }
  if (i < BATCH * FCAST) out[i] = outB[0];
  if (i < 2048) sync[i] = 0;   // cnt[32*32] + slots[8] + arrive[1]
}

// ---------------- persistent kernel ----------------
__global__ __launch_bounds__(256, 2) void lstm_persist(
    const f16* __restrict__ encT, const f16* __restrict__ decPW, const f16* __restrict__ decFW,
    const float* __restrict__ bE, const float* __restrict__ bP, const float* __restrict__ bF,
    const float* __restrict__ x, f16* __restrict__ h0, f16* __restrict__ h1,
    float* __restrict__ out, const float* __restrict__ outW, int* __restrict__ sync) {
  __shared__ __align__(16) f16 sA[Mrows * SAS];  // 35328 B
  __shared__ __align__(16) f16 sH[Mrows * SHS];  // 2560 B
  __shared__ int sInfo[2];

  int* cnt = sync;            // 32 groups, stride 32 ints
  int* slots = sync + 1024;
  int* arrive = sync + 1032;

  const int T = threadIdx.x;
  const int w = T >> 6, lane = T & 63, l4 = lane & 15, q = lane >> 4;
  const int j = l4 & 7;           // unit within wave's 8
  const bool lo = (l4 < 8);       // lo lanes own gates i,g; hi lanes f,o

  int xcd;
  asm("s_getreg_b32 %0, hwreg(HW_REG_XCC_ID)" : "=s"(xcd));
  xcd &= 7;

  // ---- one-time self-organization (agent scope, release/acquire-sound) ----
  if (T == 0) {
    int r = __hip_atomic_fetch_add(&slots[xcd], 1, __ATOMIC_RELAXED, __HIP_MEMORY_SCOPE_AGENT);
    sInfo[0] = r;
    __hip_atomic_fetch_add(arrive, 1, __ATOMIC_RELEASE, __HIP_MEMORY_SCOPE_AGENT);
    while (__hip_atomic_load(arrive, __ATOMIC_ACQUIRE, __HIP_MEMORY_SCOPE_AGENT) < 512)
      __builtin_amdgcn_s_sleep(2);
    __threadfence();
    int ok = 1;
    for (int xx = 0; xx < 8; ++xx)
      ok &= (__hip_atomic_load(&slots[xx], __ATOMIC_RELAXED, __HIP_MEMORY_SCOPE_AGENT) == 64);
    sInfo[1] = ok;
  }
  __syncthreads();
  const int rank = sInfo[0];
  const bool uni = (sInfo[1] != 0);
  int group, nslot;
  if (uni) { group = xcd * 4 + (rank >> 4); nslot = rank & 15; }  // XCD-local group
  else     { group = (int)blockIdx.x >> 4;  nslot = (int)blockIdx.x & 15; }
  const int m0 = group * Mrows, n0 = nslot * 128, u0 = nslot * 32;
  int* myCnt = cnt + group * 32;

  f16x8 bw[2][17];   // 136 VGPRs — dominant pressure; d released before GEMM
  float bias_r[4];
  float cst[4];      // c-state: lo lanes tile0 rows, hi lanes tile1 rows
#pragma unroll
  for (int r = 0; r < 4; ++r) cst[r] = 0.f;

  const int myUnit = u0 + w * 8 + j;

  auto loadB = [&](const f16* WT, const float* bias) {
#pragma unroll
    for (int ct = 0; ct < 2; ++ct) {
      const f16* base = &WT[(size_t)(n0 + w * 32 + ct * 16 + l4) * K2 + q * 8];
#pragma unroll
      for (int ks = 0; ks < 17; ++ks) bw[ct][ks] = *(const f16x8*)(base + ks * 32);
    }
#pragma unroll
    for (int g = 0; g < 4; ++g)
      bias_r[g] = bias[n0 + w * 32 + (g >> 1) * 16 + (g & 1) * 8 + j];
  };

  loadB(encT, bE);
  float ow_r = 0.f;

  // staging geometry: id = T + 256*jj -> row = (T>>6) + 4*jj, c8 = (T&63)*8 (const)
  const int c8s = (lane)*8;                 // (T&63)*8
  const int row0 = w;                       // T>>6

  for (int s = 0; s < SEQ + FCAST; ++s) {
    const bool enc = s < SEQ;
    if (s == SEQ) {
      loadB(decPW, bP);
      ow_r = outW[myUnit];
    } else if (s == SEQ + 1) {
      loadB(decFW, bF);
    }

    if (s > 0) {
      asm volatile("s_waitcnt vmcnt(0)" ::: "memory");
      __syncthreads();
      if (T == 0) {
        if (uni) {
          atomic_add_l2(myCnt, 1);
          while (atomic_add_l2(myCnt, 0) < 16 * s) __builtin_amdgcn_s_sleep(1);
        } else {
          __hip_atomic_fetch_add(myCnt, 1, __ATOMIC_RELAXED, __HIP_MEMORY_SCOPE_AGENT);
          while (__hip_atomic_load(myCnt, __ATOMIC_RELAXED, __HIP_MEMORY_SCOPE_AGENT) < 16 * s)
            __builtin_amdgcn_s_sleep(2);
        }
      }
      __syncthreads();
    }

    const f16* hin = (s & 1) ? h1 : h0;
    f16* hout = (s & 1) ? h0 : h1;

    // ---- x via compiler loads (tracked; issued first, drained by the mega-wait) ----
    const bool hasx = enc && (T < Mrows);
    float4 xa, xb;
    if (hasx) {
      const float* xp = &x[((size_t)(m0 + T) * SEQ + s) * 8];
      xa = *(const float4*)xp;
      xb = *(const float4*)(xp + 4);
    }

    // ---- h staging: ONE asm block, 8 loads + waitcnt INSIDE (spill-safe) ----
    {
      const f16* pb = &hin[(size_t)(m0 + row0) * Hh + c8s];
      const f16 *p0 = pb,            *p1 = pb + 4 * Hh,  *p2 = pb + 8 * Hh,  *p3 = pb + 12 * Hh;
      const f16 *p4 = pb + 16 * Hh,  *p5 = pb + 20 * Hh, *p6 = pb + 24 * Hh, *p7 = pb + 28 * Hh;
      f16x8 d0, d1, d2, d3, d4, d5, d6, d7;
      if (!uni) {
        asm volatile(
            "global_load_dwordx4 %0, %8, off sc0 sc1\n\t"
            "global_load_dwordx4 %1, %9, off sc0 sc1\n\t"
            "global_load_dwordx4 %2, %10, off sc0 sc1\n\t"
            "global_load_dwordx4 %3, %11, off sc0 sc1\n\t"
            "global_load_dwordx4 %4, %12, off sc0 sc1\n\t"
            "global_load_dwordx4 %5, %13, off sc0 sc1\n\t"
            "global_load_dwordx4 %6, %14, off sc0 sc1\n\t"
            "global_load_dwordx4 %7, %15, off sc0 sc1\n\t"
            "s_waitcnt vmcnt(0)"
            : "=&v"(d0), "=&v"(d1), "=&v"(d2), "=&v"(d3),
              "=&v"(d4), "=&v"(d5), "=&v"(d6), "=&v"(d7)
            : "v"(p0), "v"(p1), "v"(p2), "v"(p3), "v"(p4), "v"(p5), "v"(p6), "v"(p7)
            : "memory");
      } else {
        asm volatile(
            "global_load_dwordx4 %0, %8, off sc0\n\t"
            "global_load_dwordx4 %1, %9, off sc0\n\t"
            "global_load_dwordx4 %2, %10, off sc0\n\t"
            "global_load_dwordx4 %3, %11, off sc0\n\t"
            "global_load_dwordx4 %4, %12, off sc0\n\t"
            "global_load_dwordx4 %5, %13, off sc0\n\t"
            "global_load_dwordx4 %6, %14, off sc0\n\t"
            "global_load_dwordx4 %7, %15, off sc0\n\t"
            "s_waitcnt vmcnt(0)"
            : "=&v"(d0), "=&v"(d1), "=&v"(d2), "=&v"(d3),
              "=&v"(d4), "=&v"(d5), "=&v"(d6), "=&v"(d7)
            : "v"(p0), "v"(p1), "v"(p2), "v"(p3), "v"(p4), "v"(p5), "v"(p6), "v"(p7)
            : "memory");
      }
      f16* sb = &sA[row0 * SAS + c8s];
      *(f16x8*)(sb + 0 * 4 * SAS) = d0;
      *(f16x8*)(sb + 1 * 4 * SAS) = d1;
      *(f16x8*)(sb + 2 * 4 * SAS) = d2;
      *(f16x8*)(sb + 3 * 4 * SAS) = d3;
      *(f16x8*)(sb + 4 * 4 * SAS) = d4;
      *(f16x8*)(sb + 5 * 4 * SAS) = d5;
      *(f16x8*)(sb + 6 * 4 * SAS) = d6;
      *(f16x8*)(sb + 7 * 4 * SAS) = d7;
    }
    if (hasx) {
      f16x8 xv = {(f16)xa.x, (f16)xa.y, (f16)xa.z, (f16)xa.w,
                  (f16)xb.x, (f16)xb.y, (f16)xb.z, (f16)xb.w};
      f16x8 z = {(f16)0.f, (f16)0.f, (f16)0.f, (f16)0.f, (f16)0.f, (f16)0.f, (f16)0.f, (f16)0.f};
      *(f16x8*)&sA[T * SAS + 512] = xv;
      *(f16x8*)&sA[T * SAS + 520] = z;
      *(f16x8*)&sA[T * SAS + 528] = z;
      *(f16x8*)&sA[T * SAS + 536] = z;
    }
    __syncthreads();

    // ---- GEMM: 2 M-tiles x 2 N-tiles x 17(enc)/16(dec) K-steps ----
    f32x4 acc[2][2];
#pragma unroll
    for (int a = 0; a < 2; ++a)
#pragma unroll
      for (int c = 0; c < 2; ++c) acc[a][c] = (f32x4){0.f, 0.f, 0.f, 0.f};

    auto mac = [&](int at, int ks) {
      int ko = ks * 32 + q * 8;
      f16x8 af = *(const f16x8*)&sA[(at * 16 + l4) * SAS + ko];
      acc[at][0] = __builtin_amdgcn_mfma_f32_16x16x32_f16(af, bw[0][ks], acc[at][0], 0, 0, 0);
      acc[at][1] = __builtin_amdgcn_mfma_f32_16x16x32_f16(af, bw[1][ks], acc[at][1], 0, 0, 0);
    };
    if (enc) {
#pragma unroll
      for (int ks = 0; ks < 17; ++ks) {
        mac(0, ks);
        mac(1, ks);
      }
    } else {
#pragma unroll
      for (int ks = 0; ks < 16; ++ks) {
        mac(0, ks);
        mac(1, ks);
      }
    }

    // ---- pointwise: lane pair l4 <-> l4+8 exchanges (i,g)<->(f,o), tiles 0<->1 ----
    // lo lane finalizes tile0 rows (0..15), hi lane tile1 rows (16..31).
#pragma unroll
    for (int r = 0; r < 4; ++r) {
      // lo's acc[1] holds (i,g) of tile1 -> hi needs; hi's acc[0] holds (f,o) of tile0 -> lo needs
      float payload0 = lo ? acc[1][0][r] : acc[0][0][r];
      float payload1 = lo ? acc[1][1][r] : acc[0][1][r];
      float recv0 = __shfl_xor(payload0, 8, 16);
      float recv1 = __shfl_xor(payload1, 8, 16);
      float gi = lo ? acc[0][0][r] : recv0;
      float gf = lo ? recv0 : acc[1][0][r];
      float gg_ = lo ? acc[0][1][r] : recv1;
      float go = lo ? recv1 : acc[1][1][r];
      float pi = gi + bias_r[0];
      float pf = gf + bias_r[1];
      float pg = gg_ + bias_r[2];
      float po = go + bias_r[3];
      float ig = sigf(pi), fg = sigf(pf), gg = tanhf_(pg), og = sigf(po);
      float cn = fg * cst[r] + ig * gg;
      cst[r] = cn;
      float hn = og * tanhf_(cn);
      int at = lo ? 0 : 1;
      int row = at * 16 + q * 4 + r;
      sH[row * SHS + w * 8 + j] = (f16)hn;
      if (!enc) {
        float pp = hn * ow_r;
        pp += __shfl_xor(pp, 1, 16);
        pp += __shfl_xor(pp, 2, 16);
        pp += __shfl_xor(pp, 4, 16);
        if (j == 0) atomicAdd(&out[(m0 + row) * FCAST + (s - SEQ)], pp);
      }
    }
    __syncthreads();

    // ---- coalesced h store: 32 rows x 64 B (threads 0..127) ----
    if (T < 128) {
      int row = T >> 2, seg = T & 3;
      f16x8 hv = *(const f16x8*)&sH[row * SHS + seg * 8];
      st16(&hout[(size_t)(m0 + row) * Hh + u0 + seg * 8], hv, !uni);
    }
  }
}

extern "C" void kernel_launch(void* const* d_in, const int* in_sizes, int n_in, void* d_out,
                              int out_size, void* d_ws, size_t ws_size, hipStream_t stream) {
  const float* x = (const float*)d_in[0];
  const float* encWih = (const float*)d_in[1];
  const float* encWhh = (const float*)d_in[2];
  const float* encBih = (const float*)d_in[3];
  const float* encBhh = (const float*)d_in[4];
  const float* decWih = (const float*)d_in[5];
  const float* decWhh = (const float*)d_in[6];
  const float* decBih = (const float*)d_in[7];
  const float* decBhh = (const float*)d_in[8];
  const float* outW = (const float*)d_in[9];
  const float* outB = (const float*)d_in[10];
  float* out = (float*)d_out;

  char* ws = (char*)d_ws;
  f16* encT = (f16*)ws;
  f16* decPW = encT + 2048 * K2;
  f16* decFW = decPW + 2048 * K2;
  f16* h0 = decFW + 2048 * K2;
  f16* h1 = h0 + BATCH * Hh;
  float* bE = (float*)(h1 + BATCH * Hh);
  float* bP = bE + 2048;
  float* bF = bP + 2048;
  int* sync = (int*)(bF + 2048);

  prep_weights<<<544, 256, 0, stream>>>(encWih, encWhh, decWih, decWhh, encBih, encBhh, decBih,
                                        decBhh, outW, outB, encT, decPW, decFW, bE, bP, bF);
  init_state<<<2048, 256, 0, stream>>>(h0, h1, out, outB, sync);
  lstm_persist<<<512, 256, 0, stream>>>(encT, decPW, decFW, bE, bP, bF, x, h0, h1, out, outW, sync);
}

// Round 11
// 2376.892 us; speedup vs baseline: 1.7028x; 1.7028x over previous
//
#include <hip/hip_runtime.h>

// LSTM encoder-decoder, MI355X. B=1024, S=256, IN=8, H=512, F=96.
// R17: R12 (2451us, verified) + two in-structure fixes:
//  (1) LDS granule-swizzle: A-reads were an inherent 8-way bank conflict (row
//      stride 276 dw == 20 mod 32; all offsets 16B-granular -> only 8 banks).
//      Rotate 16B granule-pairs within each 64B K-block by (row&3):
//      store k of row r at ks*32 + (((k>>3)+r)&3)*8 + (k&7); read fragment q at
//      ks*32 + (((q+l4)&3)<<3). b128 stays contiguous+aligned. 8-way -> ~4-way.
//      (ks=16 x-block unswizzled.) SQ_LDS_BANK_CONFLICT 1.05e8 -> expect ~0.35e8.
//  (2) x prefetch one step ahead via COMPILER loads issued after the h-store;
//      loop-top wait = vmcnt(2) for wave 0 during enc (h-store is oldest ->
//      still drained; 2 x-loads fly across the barrier), vmcnt(0) otherwise.
// !! LEDGER (hard rules): (a) cross-wg spin-waits are atomic-RMW ONLY — plain-load
// polls hang (R7/R8/R11). (b) asm-load dest consumed by register-only ops needs
// in-asm waitcnt or sched_barrier (R13-R15 NaN; R16 confirmed in-asm fix). (c) ANY
// 2-waves/EU request caps arch-VGPR at 128 (R9/R10/R16 measured) < bw's 136 ->
// 2 waves/SIMD is structurally impossible here; this kernel is 1 blk/CU, cap 512.
// Structure: 256 wgs x 256 thr, 16 groups x 64 rows, 16 wgs/group x 128 gate-cols.
// Per wave: bw[2][17]=136 VGPRs, acc[4][2], d[16] staging; ~210 VGPR, no spill.
// Phased staging: issue 16 h-loads; vmcnt(8) -> rows 0..31; sync; GEMM at=0,1
// ks<16 while rows 32..63 in flight; vmcnt(0) -> write rest + x; sync; remainder.
// Mode A: XCD-self-organized groups, h via XCD-local L2 (plain stores + sc0
// loads), barrier = TCC atomics. Mode B fallback: agent-scope MALL path.

#define Hh 512
#define K2 544       // 512 h + 8 x + 24 zero pad
#define BATCH 1024
#define SEQ 256
#define FCAST 96
#define Mrows 64
#define SAS 552      // sA stride (f16)
#define SHS 40       // sH stride (f16): 80 B row

typedef _Float16 f16;
typedef _Float16 f16x8 __attribute__((ext_vector_type(8)));
typedef float f32x4 __attribute__((ext_vector_type(4)));

__device__ __forceinline__ float sigf(float v) { return 1.0f / (1.0f + __expf(-v)); }
__device__ __forceinline__ float tanhf_(float v) { return 1.0f - 2.0f / (__expf(2.0f * v) + 1.0f); }

__device__ __forceinline__ f16x8 ld16(const f16* p, bool byp) {
  f16x8 d;
  if (byp) asm volatile("global_load_dwordx4 %0, %1, off sc0 sc1" : "=v"(d) : "v"(p) : "memory");
  else     asm volatile("global_load_dwordx4 %0, %1, off sc0"     : "=v"(d) : "v"(p) : "memory");
  return d;
}
__device__ __forceinline__ void st16(f16* p, f16x8 v, bool byp) {
  if (byp) asm volatile("global_store_dwordx4 %0, %1, off sc0 sc1" :: "v"(p), "v"(v) : "memory");
  else     asm volatile("global_store_dwordx4 %0, %1, off"         :: "v"(p), "v"(v) : "memory");
}
__device__ __forceinline__ int atomic_add_l2(int* p, int v) {
  int old;
  asm volatile("global_atomic_add %0, %1, %2, off sc0\n\ts_waitcnt vmcnt(0)"
               : "=v"(old) : "v"(p), "v"(v) : "memory");
  return old;
}

// ---------------- prep: permute + fp16-convert + fold weights ----------------
// global col n: nslot=n>>7, c=n&127, w=c>>5, cc=c&31, ct=cc>>4, l4=cc&15;
// gate=ct*2+(l4>>3), j=l4&7, unit=nslot*32+w*8+j; source row r=gate*512+unit.
// K: [0,512)=Whh, [512,520)=Wih(enc), [520,544)=0.
__global__ void prep_weights(const float* __restrict__ encWih, const float* __restrict__ encWhh,
                             const float* __restrict__ decWih, const float* __restrict__ decWhh,
                             const float* __restrict__ encBih, const float* __restrict__ encBhh,
                             const float* __restrict__ decBih, const float* __restrict__ decBhh,
                             const float* __restrict__ outW, const float* __restrict__ outB,
                             f16* __restrict__ encT, f16* __restrict__ decPW, f16* __restrict__ decFW,
                             float* __restrict__ bE, float* __restrict__ bP, float* __restrict__ bF) {
  int id = blockIdx.x * 256 + threadIdx.x;
  if (id >= 2048 * 68) return;
  int n = id / 68, c8 = id % 68;
  int nslot = n >> 7, c = n & 127, w = c >> 5, cc = c & 31, ct = cc >> 4, l4v = cc & 15;
  int g = ct * 2 + (l4v >> 3), j = l4v & 7;
  int unit = nslot * 32 + w * 8 + j, r = g * Hh + unit;
  size_t o = (size_t)n * K2 + c8 * 8;
  if (c8 < 64) {
    float dwih = decWih[r];
#pragma unroll
    for (int e = 0; e < 8; ++e) {
      int k = c8 * 8 + e;
      encT[o + e] = (f16)encWhh[(size_t)r * Hh + k];
      float dw = decWhh[(size_t)r * Hh + k];
      decPW[o + e] = (f16)dw;
      decFW[o + e] = (f16)(dw + outW[k] * dwih);
    }
  } else if (c8 == 64) {
#pragma unroll
    for (int e = 0; e < 8; ++e) {
      encT[o + e] = (f16)encWih[r * 8 + e];
      decPW[o + e] = (f16)0.f;
      decFW[o + e] = (f16)0.f;
    }
  } else {
#pragma unroll
    for (int e = 0; e < 8; ++e) {
      encT[o + e] = (f16)0.f;
      decPW[o + e] = (f16)0.f;
      decFW[o + e] = (f16)0.f;
    }
  }
  if (c8 == 0) {
    bE[n] = encBih[r] + encBhh[r];
    float bd = decBih[r] + decBhh[r];
    bP[n] = bd;
    bF[n] = bd + outB[0] * decWih[r];
  }
}

__global__ void init_state(f16* __restrict__ h0, f16* __restrict__ h1, float* __restrict__ out,
                           const float* __restrict__ outB, int* __restrict__ sync) {
  int i = blockIdx.x * 256 + threadIdx.x;
  if (i < BATCH * Hh) { h0[i] = (f16)0.f; h1[i] = (f16)0.f; }
  if (i < BATCH * FCAST) out[i] = outB[0];
  if (i < 2048) sync[i] = 0;   // cnt[16*32] + slots[8] + arrive[1]
}

// ---------------- persistent kernel ----------------
__global__ __launch_bounds__(256, 1) void lstm_persist(
    const f16* __restrict__ encT, const f16* __restrict__ decPW, const f16* __restrict__ decFW,
    const float* __restrict__ bE, const float* __restrict__ bP, const float* __restrict__ bF,
    const float* __restrict__ x, f16* __restrict__ h0, f16* __restrict__ h1,
    float* __restrict__ out, const float* __restrict__ outW, int* __restrict__ sync) {
  __shared__ __align__(16) f16 sA[Mrows * SAS];  // 70656 B
  __shared__ __align__(16) f16 sH[Mrows * SHS];  // 5120 B
  __shared__ int sInfo[2];

  int* cnt = sync;            // 16 groups, stride 32 ints
  int* slots = sync + 1024;
  int* arrive = sync + 1032;

  const int T = threadIdx.x;
  const int w = T >> 6, lane = T & 63, l4 = lane & 15, q = lane >> 4;
  const int j = l4 & 7;           // unit within wave's 8
  const bool lo = (l4 < 8);       // lo lanes own gates i,g; hi lanes f,o
  const int qr8 = ((q + l4) & 3) << 3;   // swizzled fragment offset (row==l4 mod 4)

  int xcd;
  asm("s_getreg_b32 %0, hwreg(HW_REG_XCC_ID)" : "=s"(xcd));
  xcd &= 7;

  // ---- one-time self-organization (agent scope, release/acquire-sound) ----
  if (T == 0) {
    int r = __hip_atomic_fetch_add(&slots[xcd], 1, __ATOMIC_RELAXED, __HIP_MEMORY_SCOPE_AGENT);
    sInfo[0] = r;
    __hip_atomic_fetch_add(arrive, 1, __ATOMIC_RELEASE, __HIP_MEMORY_SCOPE_AGENT);
    while (__hip_atomic_load(arrive, __ATOMIC_ACQUIRE, __HIP_MEMORY_SCOPE_AGENT) < 256)
      __builtin_amdgcn_s_sleep(2);
    __threadfence();
    int ok = 1;
    for (int xx = 0; xx < 8; ++xx)
      ok &= (__hip_atomic_load(&slots[xx], __ATOMIC_RELAXED, __HIP_MEMORY_SCOPE_AGENT) == 32);
    sInfo[1] = ok;
  }
  __syncthreads();
  const int rank = sInfo[0];
  const bool uni = (sInfo[1] != 0);
  int group, nslot;
  if (uni) { group = xcd * 2 + (rank >> 4); nslot = rank & 15; }  // XCD-local group
  else     { group = (int)blockIdx.x >> 4;  nslot = (int)blockIdx.x & 15; }
  const int m0 = group * Mrows, n0 = nslot * 128, u0 = nslot * 32;
  int* myCnt = cnt + group * 32;

  f16x8 bw[2][17];   // 136 VGPRs — fits under 512 cap, no spill
  float bias_r[4];
  float cst[2][4];   // c-state: lo lanes rows at{0,1}, hi lanes at{2,3}
#pragma unroll
  for (int a = 0; a < 2; ++a)
#pragma unroll
    for (int r = 0; r < 4; ++r) cst[a][r] = 0.f;

  const int myUnit = u0 + w * 8 + j;

  auto loadB = [&](const f16* WT, const float* bias) {
#pragma unroll
    for (int ct = 0; ct < 2; ++ct) {
      const f16* base = &WT[(size_t)(n0 + w * 32 + ct * 16 + l4) * K2 + q * 8];
#pragma unroll
      for (int ks = 0; ks < 17; ++ks) bw[ct][ks] = *(const f16x8*)(base + ks * 32);
    }
#pragma unroll
    for (int g = 0; g < 4; ++g)
      bias_r[g] = bias[n0 + w * 32 + (g >> 1) * 16 + (g & 1) * 8 + j];
  };

  loadB(encT, bE);
  float ow_r = 0.f;

  // ---- x prefetch for step 0 (compiler loads; compiler tracks the waits) ----
  float4 xa, xb;
  if (T < Mrows) {
    const float* xp = &x[((size_t)(m0 + T) * SEQ + 0) * 8];
    xa = *(const float4*)xp;
    xb = *(const float4*)(xp + 4);
  }

  for (int s = 0; s < SEQ + FCAST; ++s) {
    const bool enc = s < SEQ;
    if (s == SEQ) {
      loadB(decPW, bP);
      ow_r = outW[myUnit];
    } else if (s == SEQ + 1) {
      loadB(decFW, bF);
    }

    if (s > 0) {
      // wave 0 during enc keeps its 2 x-prefetch loads in flight; the h-store is
      // the OLDEST outstanding op so vmcnt(2) still drains it. Others drain all.
      if (s < SEQ && w == 0) asm volatile("s_waitcnt vmcnt(2)" ::: "memory");
      else                   asm volatile("s_waitcnt vmcnt(0)" ::: "memory");
      __syncthreads();
      if (T == 0) {
        if (uni) {
          atomic_add_l2(myCnt, 1);
          while (atomic_add_l2(myCnt, 0) < 16 * s) __builtin_amdgcn_s_sleep(1);
        } else {
          __hip_atomic_fetch_add(myCnt, 1, __ATOMIC_RELAXED, __HIP_MEMORY_SCOPE_AGENT);
          while (__hip_atomic_load(myCnt, __ATOMIC_RELAXED, __HIP_MEMORY_SCOPE_AGENT) < 16 * s)
            __builtin_amdgcn_s_sleep(2);
        }
      }
      __syncthreads();
    }

    const f16* hin = (s & 1) ? h1 : h0;
    f16* hout = (s & 1) ? h0 : h1;

    // ---- phased staging: issue all 16 h-loads, wait in two halves ----
    f16x8 d[16];
#pragma unroll
    for (int jj = 0; jj < 16; ++jj) {
      int id = T + 256 * jj;
      int row = id >> 6, c8 = (id & 63) * 8;
      d[jj] = ld16(&hin[(size_t)(m0 + row) * Hh + c8], !uni);
    }
    asm volatile("s_waitcnt vmcnt(8)" ::: "memory");   // oldest (x +) 8 h-loads done
    // swizzled LDS write: granule-pair ((c8>>3)+row)&3 within each 64B K-block
#pragma unroll
    for (int jj = 0; jj < 8; ++jj) {
      int id = T + 256 * jj;
      int row = id >> 6, c8 = (id & 63) * 8;
      int csw = (c8 & ~31) | ((((c8 >> 3) + row) & 3) << 3);
      *(f16x8*)&sA[row * SAS + csw] = d[jj];
    }
    __syncthreads();

    // ---- GEMM phase 1: at=0,1 over h-cols (ks 0..15); rows 32..63 in flight ----
    f32x4 acc[4][2];
#pragma unroll
    for (int a = 0; a < 4; ++a)
#pragma unroll
      for (int c = 0; c < 2; ++c) acc[a][c] = (f32x4){0.f, 0.f, 0.f, 0.f};

    auto mac = [&](int at, int ks) {
      int ko = (ks < 16) ? (ks * 32 + qr8) : (512 + q * 8);   // x-block unswizzled
      f16x8 af = *(const f16x8*)&sA[(at * 16 + l4) * SAS + ko];
      acc[at][0] = __builtin_amdgcn_mfma_f32_16x16x32_f16(af, bw[0][ks], acc[at][0], 0, 0, 0);
      acc[at][1] = __builtin_amdgcn_mfma_f32_16x16x32_f16(af, bw[1][ks], acc[at][1], 0, 0, 0);
    };
#pragma unroll
    for (int ks = 0; ks < 16; ++ks) {
      mac(0, ks);
      mac(1, ks);
    }

    // ---- finish staging: rows 32..63 + x cols ----
    asm volatile("s_waitcnt vmcnt(0)" ::: "memory");
#pragma unroll
    for (int jj = 8; jj < 16; ++jj) {
      int id = T + 256 * jj;
      int row = id >> 6, c8 = (id & 63) * 8;
      int csw = (c8 & ~31) | ((((c8 >> 3) + row) & 3) << 3);
      *(f16x8*)&sA[row * SAS + csw] = d[jj];
    }
    if (enc && T < Mrows) {
      f16x8 xv = {(f16)xa.x, (f16)xa.y, (f16)xa.z, (f16)xa.w,
                  (f16)xb.x, (f16)xb.y, (f16)xb.z, (f16)xb.w};
      f16x8 z = {(f16)0.f, (f16)0.f, (f16)0.f, (f16)0.f, (f16)0.f, (f16)0.f, (f16)0.f, (f16)0.f};
      *(f16x8*)&sA[T * SAS + 512] = xv;
      *(f16x8*)&sA[T * SAS + 520] = z;
      *(f16x8*)&sA[T * SAS + 528] = z;
      *(f16x8*)&sA[T * SAS + 536] = z;
    }
    __syncthreads();

    // ---- GEMM phase 2: x-cols of at=0,1; all of at=2,3 ----
    if (enc) {
      mac(0, 16);
      mac(1, 16);
    }
#pragma unroll
    for (int ks = 0; ks < 16; ++ks) {
      mac(2, ks);
      mac(3, ks);
    }
    if (enc) {
      mac(2, 16);
      mac(3, 16);
    }

    // ---- pointwise: lane pair l4 <-> l4+8 exchanges (i,g)<->(f,o) ----
    // lo lane handles at 0..1 (rows 0..31), hi lane at 2..3 (rows 32..63).
#pragma unroll
    for (int ah = 0; ah < 2; ++ah) {
#pragma unroll
      for (int r = 0; r < 4; ++r) {
        int atL = ah;          // lo's tile
        int atH = ah + 2;      // hi's tile
        float xiL = acc[atL][0][r], xgL = acc[atL][1][r];  // lo owns i,g ; hi owns f,o
        float xiH = acc[atH][0][r], xgH = acc[atH][1][r];
        float payload0 = lo ? xiH : xiL;   // ct=0 value partner needs
        float payload1 = lo ? xgH : xgL;   // ct=1 value partner needs
        float pf_recv = __shfl_xor(payload0, 8, 16);
        float po_recv = __shfl_xor(payload1, 8, 16);
        float gi = lo ? xiL : pf_recv;
        float gf = lo ? pf_recv : xiH;
        float gg_ = lo ? xgL : po_recv;
        float go = lo ? po_recv : xgH;
        float pi = gi + bias_r[0];
        float pf = gf + bias_r[1];
        float pg = gg_ + bias_r[2];
        float po = go + bias_r[3];
        float ig = sigf(pi), fg = sigf(pf), gg = tanhf_(pg), og = sigf(po);
        float cn = fg * cst[ah][r] + ig * gg;
        cst[ah][r] = cn;
        float hn = og * tanhf_(cn);
        int at = lo ? atL : atH;
        int row = at * 16 + q * 4 + r;
        sH[row * SHS + w * 8 + j] = (f16)hn;
        if (!enc) {
          float pp = hn * ow_r;
          pp += __shfl_xor(pp, 1, 16);
          pp += __shfl_xor(pp, 2, 16);
          pp += __shfl_xor(pp, 4, 16);
          if (j == 0) atomicAdd(&out[(m0 + row) * FCAST + (s - SEQ)], pp);
        }
      }
    }
    __syncthreads();

    // ---- coalesced h store: 64 rows x 64 B ----
    {
      int row = T >> 2, seg = T & 3;
      f16x8 hv = *(const f16x8*)&sH[row * SHS + seg * 8];
      st16(&hout[(size_t)(m0 + row) * Hh + u0 + seg * 8], hv, !uni);
    }

    // ---- x prefetch for step s+1 (issued AFTER the h-store so the store stays
    //      oldest; flies across the barrier; compiler-tracked) ----
    if (s + 1 < SEQ && T < Mrows) {
      const float* xp = &x[((size_t)(m0 + T) * SEQ + (s + 1)) * 8];
      xa = *(const float4*)xp;
      xb = *(const float4*)(xp + 4);
    }
  }
}

extern "C" void kernel_launch(void* const* d_in, const int* in_sizes, int n_in, void* d_out,
                              int out_size, void* d_ws, size_t ws_size, hipStream_t stream) {
  const float* x = (const float*)d_in[0];
  const float* encWih = (const float*)d_in[1];
  const float* encWhh = (const float*)d_in[2];
  const float* encBih = (const float*)d_in[3];
  const float* encBhh = (const float*)d_in[4];
  const float* decWih = (const float*)d_in[5];
  const float* decWhh = (const float*)d_in[6];
  const float* decBih = (const float*)d_in[7];
  const float* decBhh = (const float*)d_in[8];
  const float* outW = (const float*)d_in[9];
  const float* outB = (const float*)d_in[10];
  float* out = (float*)d_out;

  char* ws = (char*)d_ws;
  f16* encT = (f16*)ws;
  f16* decPW = encT + 2048 * K2;
  f16* decFW = decPW + 2048 * K2;
  f16* h0 = decFW + 2048 * K2;
  f16* h1 = h0 + BATCH * Hh;
  float* bE = (float*)(h1 + BATCH * Hh);
  float* bP = bE + 2048;
  float* bF = bP + 2048;
  int* sync = (int*)(bF + 2048);

  prep_weights<<<544, 256, 0, stream>>>(encWih, encWhh, decWih, decWhh, encBih, encBhh, decBih,
                                        decBhh, outW, outB, encT, decPW, decFW, bE, bP, bF);
  init_state<<<2048, 256, 0, stream>>>(h0, h1, out, outB, sync);
  lstm_persist<<<256, 256, 0, stream>>>(encT, decPW, decFW, bE, bP, bF, x, h0, h1, out, outW, sync);
}